// Round 15
// baseline (86.784 us; speedup 1.0000x reference)
//
#include <hip/hip_runtime.h>

// Störmer-Verlet / leapfrog (kick-drift-kick) for q'' = -sin(q), NSTEPS=8.
// Accuracy: PROVEN on-bench — leapfrog n=8 absmax = 0.03125, bit-identical to
// FR4 n=25 (fp32-noise floor; threshold 0.149, ~5x margin). Numerics
// unchanged from R12/R13.
//
// Perf: R8-R13 show a sticky 9-13us non-issue term (memory burst + ramp) that
// in-thread chunk pipelines barely dent (residency caps at 8 waves/SIMD).
// This round uses CROSS-ROUND self-pipelining: tiny wave quantum
// (float2/thread: 2 loads -> ~370 cyc compute -> 2 NT stores), 8192 blocks =
// 4 sequential rounds. Round-k waves launch as round-(k-1) waves retire in
// memory-service order -> round-k reads overlap round-(k-1) compute/stores at
// wave granularity; only the last round's store tail (~1.3us) is exposed.
//
// R14 BUG FIXED: out is float*, kq starts at float offset n (NOT n/2 — that
// clobbered kp's second half and left kq's slot zeroed).

#define NSTEPS 8

typedef float v2fn __attribute__((ext_vector_type(2)));

__global__ __launch_bounds__(256) void symp_kernel(
    const float2* __restrict__ p0,
    const float2* __restrict__ q0,
    const float* __restrict__ t0,
    const float* __restrict__ t1,
    v2fn* __restrict__ out_p,
    v2fn* __restrict__ out_q,
    int nthreads)
{
    const int tid = blockIdx.x * blockDim.x + threadIdx.x;
    if (tid >= nthreads) return;

    const float h = (t1[0] - t0[0]) * (1.0f / (float)NSTEPS);

    const float INV2PI = 0.15915494309189535f;
    const float TWOPI  = 6.283185307179586f;

    const float hr  = h * INV2PI;     // drift coefficient (revolution units)
    const float nk  = -h;             // full kick: P += -h * sin(2*pi*Q)
    const float nk2 = -0.5f * h;      // half kick

    float2 pv = p0[tid];
    float2 qv = q0[tid];

    float P[2] = {pv.x, pv.y};
    float Q[2] = {qv.x * INV2PI, qv.y * INV2PI};

    // initial half kick
    #pragma unroll
    for (int j = 0; j < 2; ++j)
        P[j] = fmaf(nk2, __builtin_amdgcn_sinf(Q[j]), P[j]);

    // (n-1) x [drift + full kick]
    #pragma unroll 1
    for (int s = 0; s < NSTEPS - 1; ++s) {
        #pragma unroll
        for (int j = 0; j < 2; ++j) Q[j] = fmaf(hr, P[j], Q[j]);
        #pragma unroll
        for (int j = 0; j < 2; ++j)
            P[j] = fmaf(nk, __builtin_amdgcn_sinf(Q[j]), P[j]);
    }

    // final drift + half kick
    #pragma unroll
    for (int j = 0; j < 2; ++j) Q[j] = fmaf(hr, P[j], Q[j]);
    #pragma unroll
    for (int j = 0; j < 2; ++j)
        P[j] = fmaf(nk2, __builtin_amdgcn_sinf(Q[j]), P[j]);

    v2fn po = {P[0], P[1]};
    v2fn qo = {Q[0] * TWOPI, Q[1] * TWOPI};

    // nontemporal: write-once output, streamed to HBM during the kernel
    __builtin_nontemporal_store(po, &out_p[tid]);
    __builtin_nontemporal_store(qo, &out_q[tid]);
}

extern "C" void kernel_launch(void* const* d_in, const int* in_sizes, int n_in,
                              void* d_out, int out_size, void* d_ws, size_t ws_size,
                              hipStream_t stream) {
    const float* p0 = (const float*)d_in[0];
    const float* q0 = (const float*)d_in[1];
    const float* t0 = (const float*)d_in[2];
    const float* t1 = (const float*)d_in[3];
    float* out = (float*)d_out;  // [kp (n floats) | kq (n floats)] flat, fp32

    const int n = in_sizes[0];        // 4194304, divisible by 2
    const int nthreads = n / 2;       // 2097152 threads (float2 each)
    const int block = 256;
    const int grid = (nthreads + block - 1) / block;  // 8192 blocks = 4 rounds

    symp_kernel<<<grid, block, 0, stream>>>(
        (const float2*)p0, (const float2*)q0, t0, t1,
        (v2fn*)out, (v2fn*)(out + n), nthreads);   // kq at float offset n
}